// Round 5
// baseline (71.510 us; speedup 1.0000x reference)
//
#include <hip/hip_runtime.h>
#include <hip/hip_bf16.h>

#define B_SZ   2048
#define F_IN   1024
#define R_EMB  1024
#define F_OUT  1024
#define F_MID  2048
#define NNZ_E  65536
#define NNZ_W  131072
#define NNZ_B  512

typedef __bf16 bf16x8 __attribute__((ext_vector_type(8)));
typedef float  f32x16 __attribute__((ext_vector_type(16)));

__device__ inline void gload16(const void* g, void* l) {
    __builtin_amdgcn_global_load_lds(
        (const __attribute__((address_space(1))) void*)g,
        (__attribute__((address_space(3))) void*)l, 16, 0, 0);
}

__device__ inline ushort f2bf(float v) {
    __hip_bfloat16 h = __float2bfloat16(v);
    return *reinterpret_cast<ushort*>(&h);
}

__global__ void k_zero4(float4* __restrict__ p, int n) {
    int i = blockIdx.x * blockDim.x + threadIdx.x;
    if (i < n) p[i] = make_float4(0.f, 0.f, 0.f, 0.f);
}

// One launch for all three scatter-adds (blocks partitioned by range).
__global__ void k_scatter_fused(const int* __restrict__ er, const int* __restrict__ ec,
                                const float* __restrict__ ev,
                                const int* __restrict__ wr_, const int* __restrict__ wc_,
                                const float* __restrict__ wv,
                                const int* __restrict__ bi, const float* __restrict__ bv,
                                float* __restrict__ Ef, float* __restrict__ Wf,
                                float* __restrict__ biasd) {
    int b = blockIdx.x, t = threadIdx.x;
    if (b < NNZ_E / 256) {
        int i = b * 256 + t;
        atomicAdd(&Ef[(size_t)er[i] * F_IN + ec[i]], ev[i]);
    } else if (b < NNZ_E / 256 + NNZ_W / 256) {
        int i = (b - NNZ_E / 256) * 256 + t;
        atomicAdd(&Wf[(size_t)wr_[i] * F_MID + wc_[i]], wv[i]);
    } else {
        int i = t;
        atomicAdd(&biasd[bi[i]], bv[i]);
        i += 256;
        atomicAdd(&biasd[bi[i]], bv[i]);
    }
}

// One launch for all three f32->bf16 conversions.
__global__ void k_cvt_fused(const float4* __restrict__ x, ushort* __restrict__ x2,
                            const float4* __restrict__ Ef, ushort* __restrict__ Ebf,
                            const float4* __restrict__ Wf, ushort* __restrict__ Wbf) {
    int b = blockIdx.x, t = threadIdx.x;
    if (b < 2048) {
        int i = b * 256 + t;                 // float4 index into x
        int row = i >> 8, c4 = i & 255;      // 256 float4 per row of 1024
        float4 v = x[i];
        ((ushort4*)x2)[(size_t)row * (F_MID / 4) + c4] =
            make_ushort4(f2bf(v.x), f2bf(v.y), f2bf(v.z), f2bf(v.w));
    } else if (b < 3072) {
        int i = (b - 2048) * 256 + t;
        float4 v = Ef[i];
        ((ushort4*)Ebf)[i] = make_ushort4(f2bf(v.x), f2bf(v.y), f2bf(v.z), f2bf(v.w));
    } else {
        int i = (b - 3072) * 256 + t;
        float4 v = Wf[i];
        ((ushort4*)Wbf)[i] = make_ushort4(f2bf(v.x), f2bf(v.y), f2bf(v.z), f2bf(v.w));
    }
}

// C[M,N] = A[M,K] * Bm[N,K]^T with 32x32x16 bf16 MFMA.
// BM=128, BN=64, BK=128; 256 thr = 4 waves (2x2); wave tile = 64x32
// (2 A-frags of 32x32 share 1 B-frag per K-slice).
// 2-phase double-buffered LDS; XOR chunk-swizzle (pre-swizzled global source,
// linear LDS dest, swizzled ds_read — both-sides involution).
template <bool RELU_BF16>
__global__ __launch_bounds__(256)
void k_gemm(const ushort* __restrict__ A, int lda,
            const ushort* __restrict__ Bm, int ldb,
            int K,
            const float* __restrict__ bias,
            float* __restrict__ outF,
            ushort* __restrict__ outH, int ldh)
{
    constexpr int BM = 128, BN = 64, BK = 128;
    __shared__ ushort lA[2][BM * BK];   // 2 x 32 KB
    __shared__ ushort lB[2][BN * BK];   // 2 x 16 KB
    const int tid = threadIdx.x;
    const int w = tid >> 6, l = tid & 63;
    const int m0 = blockIdx.x * BM, n0 = blockIdx.y * BN;
    const int wr = w >> 1, wc = w & 1;

    f32x16 acc0 = {}, acc1 = {};
    const int nt = K / BK;

    // Staging: pass covers 16 rows; thread t -> row (t>>4), chunk slot (t&15).
    // Lane writing LDS slot s of row r fetches global chunk s ^ (r&7).
    const int srow = tid >> 4;
    const int sslot = tid & 15;

    #define STAGE(buf, k0)                                                      \
        _Pragma("unroll")                                                       \
        for (int i = 0; i < 8; ++i) {                                           \
            int row = i * 16 + srow;                                            \
            int col = (k0) + ((sslot ^ (row & 7)) << 3);                        \
            gload16(A + (size_t)(m0 + row) * lda + col,                         \
                    &lA[buf][i * 2048 + tid * 8]);                              \
        }                                                                       \
        _Pragma("unroll")                                                       \
        for (int i = 0; i < 4; ++i) {                                           \
            int row = i * 16 + srow;                                            \
            int col = (k0) + ((sslot ^ (row & 7)) << 3);                        \
            gload16(Bm + (size_t)(n0 + row) * ldb + col,                        \
                    &lB[buf][i * 2048 + tid * 8]);                              \
        }

    STAGE(0, 0);
    __syncthreads();

    const int ra0 = wr * 64 + (l & 31);
    const int ra1 = ra0 + 32;               // ra1&7 == ra0&7
    const int rb  = wc * 32 + (l & 31);
    const int xa  = (ra0 & 7), xb = (rb & 7);

    for (int t = 0; t < nt; ++t) {
        const int cur = t & 1;
        if (t + 1 < nt) STAGE(cur ^ 1, (t + 1) * BK);   // prefetch next K-tile

        const ushort* sA = &lA[cur][0];
        const ushort* sB = &lB[cur][0];
        #pragma unroll
        for (int ks = 0; ks < 8; ++ks) {
            const int c = ks * 2 + (l >> 5);            // 16B chunk index 0..15
            bf16x8 af0 = *(const bf16x8*)(sA + ra0 * BK + ((c ^ xa) << 3));
            bf16x8 af1 = *(const bf16x8*)(sA + ra1 * BK + ((c ^ xa) << 3));
            bf16x8 bg  = *(const bf16x8*)(sB + rb  * BK + ((c ^ xb) << 3));
            acc0 = __builtin_amdgcn_mfma_f32_32x32x16_bf16(af0, bg, acc0, 0, 0, 0);
            acc1 = __builtin_amdgcn_mfma_f32_32x32x16_bf16(af1, bg, acc1, 0, 0, 0);
        }
        __syncthreads();   // compiler drains vmcnt here -> buf[cur^1] ready
    }

    // C/D layout (verified m74/m101): col = lane&31, row = (r&3)+8*(r>>2)+4*(lane>>5)
    const int col = n0 + wc * 32 + (l & 31);
    const int r0  = m0 + wr * 64 + 4 * (l >> 5);
    if (RELU_BF16) {
        #pragma unroll
        for (int r = 0; r < 16; ++r) {
            int row = r0 + (r & 3) + 8 * (r >> 2);
            outH[(size_t)row * ldh + col]        = f2bf(fmaxf(acc0[r], 0.f));
            outH[(size_t)(row + 32) * ldh + col] = f2bf(fmaxf(acc1[r], 0.f));
        }
    } else {
        const float bv = bias[col];
        #pragma unroll
        for (int r = 0; r < 16; ++r) {
            int row = r0 + (r & 3) + 8 * (r >> 2);
            outF[(size_t)row * F_OUT + col]        = acc0[r] + bv;
            outF[(size_t)(row + 32) * F_OUT + col] = acc1[r] + bv;
        }
    }
    #undef STAGE
}

extern "C" void kernel_launch(void* const* d_in, const int* in_sizes, int n_in,
                              void* d_out, int out_size, void* d_ws, size_t ws_size,
                              hipStream_t stream) {
    const float* x          = (const float*)d_in[0];
    const int*   embed_rows = (const int*)  d_in[1];
    const int*   embed_cols = (const int*)  d_in[2];
    const float* embed_vals = (const float*)d_in[3];
    const int*   w_rows     = (const int*)  d_in[4];
    const int*   w_cols     = (const int*)  d_in[5];
    const float* w_vals     = (const float*)d_in[6];
    const int*   bias_idx   = (const int*)  d_in[7];
    const float* bias_vals  = (const float*)d_in[8];
    float* out = (float*)d_out;

    // Workspace layout (~26 MB):
    //   [0, 8M)          x2 bf16 [2048][2048]  (left = x, right = relu h)
    //   [8M, 16M)        W_f32 [1024][2048]
    //   [16M, 20M)       E_f32 [1024][1024]
    //   [20M, 20M+4K)    bias f32 [1024]
    //   [20M+4K, 22M+4K) E_bf16 [1024][1024]
    //   [22M+4K, 26M+4K) W_bf16 [1024][2048]
    char* ws = (char*)d_ws;
    ushort* x2    = (ushort*)ws;
    float*  Wf    = (float*)(ws + (8u << 20));
    float*  Ef    = (float*)(ws + (16u << 20));
    float*  biasd = (float*)(ws + (20u << 20));
    ushort* Ebf   = (ushort*)(ws + (20u << 20) + 4096);
    ushort* Wbf   = (ushort*)(ws + (22u << 20) + 4096);

    // 1. zero Wf | Ef | bias with our own fill kernel (12 MB + 4 KB = 786688 float4).
    //    NOT hipMemsetAsync: the runtime's fillBufferAligned for this size runs at
    //    ~285 GB/s (44 us, measured round 4); k_zero4 does it in ~3 us.
    k_zero4<<<3073, 256, 0, stream>>>((float4*)(ws + (8u << 20)), 786688);

    // 2. densify all sparse inputs (one launch)
    k_scatter_fused<<<NNZ_E / 256 + NNZ_W / 256 + 1, 256, 0, stream>>>(
        embed_rows, embed_cols, embed_vals,
        w_rows, w_cols, w_vals,
        bias_idx, bias_vals, Ef, Wf, biasd);

    // 3. all f32 -> bf16 conversions (one launch)
    k_cvt_fused<<<5120, 256, 0, stream>>>((const float4*)x, x2,
                                          (const float4*)Ef, Ebf,
                                          (const float4*)Wf, Wbf);

    // 4. GEMM1: h = relu(x @ E^T) -> bf16 into x2 right half.  M=2048,N=1024,K=1024
    k_gemm<true><<<dim3(B_SZ / 128, R_EMB / 64), 256, 0, stream>>>(
        x2, F_MID, Ebf, F_IN, F_IN, nullptr, nullptr, x2 + F_IN, F_MID);

    // 5. GEMM2: out = x2 @ W^T + bias.  M=2048,N=1024,K=2048
    k_gemm<false><<<dim3(B_SZ / 128, F_OUT / 64), 256, 0, stream>>>(
        x2, F_MID, Wbf, F_MID, F_MID, biasd, out, nullptr, 0);
}

// Round 6
// 55.357 us; speedup vs baseline: 1.2918x; 1.2918x over previous
//
#include <hip/hip_runtime.h>
#include <hip/hip_bf16.h>

#define B_SZ   2048
#define F_IN   1024
#define R_EMB  1024
#define F_OUT  1024
#define F_MID  2048
#define NNZ_E  65536
#define NNZ_W  131072
#define NNZ_B  512

typedef __bf16 bf16x8 __attribute__((ext_vector_type(8)));
typedef float  f32x4  __attribute__((ext_vector_type(4)));

__device__ inline void gload16(const void* g, void* l) {
    __builtin_amdgcn_global_load_lds(
        (const __attribute__((address_space(1))) void*)g,
        (__attribute__((address_space(3))) void*)l, 16, 0, 0);
}

__device__ inline ushort f2bf(float v) {
    __hip_bfloat16 h = __float2bfloat16(v);
    return *reinterpret_cast<ushort*>(&h);
}

__global__ void k_zero4(float4* __restrict__ p, int n) {
    int i = blockIdx.x * blockDim.x + threadIdx.x;
    if (i < n) p[i] = make_float4(0.f, 0.f, 0.f, 0.f);
}

// One launch for all three scatter-adds (blocks partitioned by range).
__global__ void k_scatter_fused(const int* __restrict__ er, const int* __restrict__ ec,
                                const float* __restrict__ ev,
                                const int* __restrict__ wr_, const int* __restrict__ wc_,
                                const float* __restrict__ wv,
                                const int* __restrict__ bi, const float* __restrict__ bv,
                                float* __restrict__ Ef, float* __restrict__ Wf,
                                float* __restrict__ biasd) {
    int b = blockIdx.x, t = threadIdx.x;
    if (b < NNZ_E / 256) {
        int i = b * 256 + t;
        atomicAdd(&Ef[(size_t)er[i] * F_IN + ec[i]], ev[i]);
    } else if (b < NNZ_E / 256 + NNZ_W / 256) {
        int i = (b - NNZ_E / 256) * 256 + t;
        atomicAdd(&Wf[(size_t)wr_[i] * F_MID + wc_[i]], wv[i]);
    } else {
        int i = t;
        atomicAdd(&biasd[bi[i]], bv[i]);
        i += 256;
        atomicAdd(&biasd[bi[i]], bv[i]);
    }
}

// One launch for all three f32->bf16 conversions.
__global__ void k_cvt_fused(const float4* __restrict__ x, ushort* __restrict__ x2,
                            const float4* __restrict__ Ef, ushort* __restrict__ Ebf,
                            const float4* __restrict__ Wf, ushort* __restrict__ Wbf) {
    int b = blockIdx.x, t = threadIdx.x;
    if (b < 2048) {
        int i = b * 256 + t;                 // float4 index into x
        int row = i >> 8, c4 = i & 255;      // 256 float4 per row of 1024
        float4 v = x[i];
        ((ushort4*)x2)[(size_t)row * (F_MID / 4) + c4] =
            make_ushort4(f2bf(v.x), f2bf(v.y), f2bf(v.z), f2bf(v.w));
    } else if (b < 3072) {
        int i = (b - 2048) * 256 + t;
        float4 v = Ef[i];
        ((ushort4*)Ebf)[i] = make_ushort4(f2bf(v.x), f2bf(v.y), f2bf(v.z), f2bf(v.w));
    } else {
        int i = (b - 3072) * 256 + t;
        float4 v = Wf[i];
        ((ushort4*)Wbf)[i] = make_ushort4(f2bf(v.x), f2bf(v.y), f2bf(v.z), f2bf(v.w));
    }
}

// Unified 64x64x64 bf16 MFMA GEMM (round-3 core: 2-phase dbuf, XOR chunk-swizzle,
// 4 waves of 32x32 wave-tiles, 16x16x32 MFMA).  All three GEMMs have
// M=2048, N=1024, K=1024, A row stride F_MID.
//   PHASE 0, by <  16: mode 0  h = relu(x @ E^T)          (bf16 into x2 right half)
//   PHASE 0, by >= 16: mode 1  out = x @ W_L^T + bias     (f32)
//   PHASE 1:           mode 2  out += h @ W_R^T           (f32 read-modify-write)
// Splitting GEMM2 at W's column 1024 makes mode 1 independent of h, so modes 0+1
// run concurrently in ONE launch: 1024 blocks = 4 blocks/CU = 16 waves/CU (TLP
// was the round-4/5 regression: 1 block/CU exposed every latency).
template <int PHASE>
__global__ __launch_bounds__(256)
void k_gemm3(const ushort* __restrict__ x2,   // [2048][2048] bf16
             const ushort* __restrict__ Ebf,  // [1024][1024] bf16
             const ushort* __restrict__ Wbf,  // [1024][2048] bf16
             const float* __restrict__ biasd, // [1024]
             float* __restrict__ out,         // [2048][1024] f32
             ushort* __restrict__ hOut)       // = x2 + F_IN (disjoint columns)
{
    constexpr int BS = 64, BK = 64, NT = 1024 / BK;
    __shared__ ushort lds[2][2][BS * BK];
    const int tid = threadIdx.x;
    const int w = tid >> 6, l = tid & 63;
    const int wr = w >> 1, wc = w & 1;
    const int la = l & 15;
    const int m0 = blockIdx.x * BS;

    int mode, ldb, n0;
    const ushort* A;
    const ushort* Bm;
    if (PHASE == 0) {
        if (blockIdx.y < 16) {
            mode = 0; A = x2;        Bm = Ebf;        ldb = F_IN;  n0 = blockIdx.y * BS;
        } else {
            mode = 1; A = x2;        Bm = Wbf;        ldb = F_MID; n0 = (blockIdx.y - 16) * BS;
        }
    } else {
        mode = 2;     A = x2 + F_IN; Bm = Wbf + F_IN; ldb = F_MID; n0 = blockIdx.y * BS;
    }

    // Staging: iter i covers 32 rows; lane writing LDS chunk-slot s of row r
    // fetches global chunk s ^ (r&7) (both-sides involution, linear LDS dest).
    const int srow = w * 8 + (l >> 3);
    const int ldst = w * 512 + l * 8;

    f32x4 acc[2][2] = {};

    #define STAGE(buf, k0)                                                        \
        _Pragma("unroll")                                                         \
        for (int i = 0; i < 2; ++i) {                                             \
            int row = i * 32 + srow;                                              \
            int scol = (k0) + ((((l & 7) ^ (row & 7))) << 3);                     \
            gload16(A  + (size_t)(m0 + row) * F_MID + scol,                       \
                    &lds[buf][0][i * 2048 + ldst]);                               \
            gload16(Bm + (size_t)(n0 + row) * ldb + scol,                         \
                    &lds[buf][1][i * 2048 + ldst]);                               \
        }

    STAGE(0, 0);
    __syncthreads();

    for (int t = 0; t < NT; ++t) {
        const int cur = t & 1;
        if (t + 1 < NT) STAGE(cur ^ 1, (t + 1) * BK);   // prefetch next K-tile

        const ushort* sA = &lds[cur][0][0];
        const ushort* sB = &lds[cur][1][0];
        #pragma unroll
        for (int ks = 0; ks < 2; ++ks) {
            const int k8 = ks * 4 + (l >> 4);           // 8-elem chunk index
            bf16x8 af[2], bg[2];
            #pragma unroll
            for (int m = 0; m < 2; ++m) {
                int row = wr * 32 + m * 16 + la;
                af[m] = *(const bf16x8*)(sA + row * BK + ((k8 ^ (row & 7)) << 3));
            }
            #pragma unroll
            for (int n = 0; n < 2; ++n) {
                int row = wc * 32 + n * 16 + la;
                bg[n] = *(const bf16x8*)(sB + row * BK + ((k8 ^ (row & 7)) << 3));
            }
            #pragma unroll
            for (int m = 0; m < 2; ++m)
                #pragma unroll
                for (int n = 0; n < 2; ++n)
                    acc[m][n] = __builtin_amdgcn_mfma_f32_16x16x32_bf16(
                        af[m], bg[n], acc[m][n], 0, 0, 0);
        }
        __syncthreads();
    }
    #undef STAGE

    // C/D layout (verified m89/m91): col = lane&15, row = (lane>>4)*4 + reg.
    const int lr = (l >> 4) * 4;
    #pragma unroll
    for (int m = 0; m < 2; ++m) {
        #pragma unroll
        for (int n = 0; n < 2; ++n) {
            const int col = n0 + wc * 32 + n * 16 + la;
            if (mode == 0) {
                #pragma unroll
                for (int j = 0; j < 4; ++j) {
                    int row = m0 + wr * 32 + m * 16 + lr + j;
                    hOut[(size_t)row * F_MID + col] = f2bf(fmaxf(acc[m][n][j], 0.f));
                }
            } else if (mode == 1) {
                const float bv = biasd[col];
                #pragma unroll
                for (int j = 0; j < 4; ++j) {
                    int row = m0 + wr * 32 + m * 16 + lr + j;
                    out[(size_t)row * F_OUT + col] = acc[m][n][j] + bv;
                }
            } else {
                #pragma unroll
                for (int j = 0; j < 4; ++j) {
                    int row = m0 + wr * 32 + m * 16 + lr + j;
                    out[(size_t)row * F_OUT + col] += acc[m][n][j];
                }
            }
        }
    }
}

extern "C" void kernel_launch(void* const* d_in, const int* in_sizes, int n_in,
                              void* d_out, int out_size, void* d_ws, size_t ws_size,
                              hipStream_t stream) {
    const float* x          = (const float*)d_in[0];
    const int*   embed_rows = (const int*)  d_in[1];
    const int*   embed_cols = (const int*)  d_in[2];
    const float* embed_vals = (const float*)d_in[3];
    const int*   w_rows     = (const int*)  d_in[4];
    const int*   w_cols     = (const int*)  d_in[5];
    const float* w_vals     = (const float*)d_in[6];
    const int*   bias_idx   = (const int*)  d_in[7];
    const float* bias_vals  = (const float*)d_in[8];
    float* out = (float*)d_out;

    // Workspace layout (~26 MB):
    //   [0, 8M)          x2 bf16 [2048][2048]  (left = x, right = relu h)
    //   [8M, 16M)        W_f32 [1024][2048]
    //   [16M, 20M)       E_f32 [1024][1024]
    //   [20M, 20M+4K)    bias f32 [1024]
    //   [20M+4K, 22M+4K) E_bf16 [1024][1024]
    //   [22M+4K, 26M+4K) W_bf16 [1024][2048]
    char* ws = (char*)d_ws;
    ushort* x2    = (ushort*)ws;
    float*  Wf    = (float*)(ws + (8u << 20));
    float*  Ef    = (float*)(ws + (16u << 20));
    float*  biasd = (float*)(ws + (20u << 20));
    ushort* Ebf   = (ushort*)(ws + (20u << 20) + 4096);
    ushort* Wbf   = (ushort*)(ws + (22u << 20) + 4096);

    // 1. zero Wf | Ef | bias (12 MB + 4 KB = 786688 float4).  Own kernel, not
    //    hipMemsetAsync (runtime fill for this size measured ~285 GB/s, round 4).
    k_zero4<<<3073, 256, 0, stream>>>((float4*)(ws + (8u << 20)), 786688);

    // 2. densify all sparse inputs (one launch)
    k_scatter_fused<<<NNZ_E / 256 + NNZ_W / 256 + 1, 256, 0, stream>>>(
        embed_rows, embed_cols, embed_vals,
        w_rows, w_cols, w_vals,
        bias_idx, bias_vals, Ef, Wf, biasd);

    // 3. all f32 -> bf16 conversions (one launch)
    k_cvt_fused<<<5120, 256, 0, stream>>>((const float4*)x, x2,
                                          (const float4*)Ef, Ebf,
                                          (const float4*)Wf, Wbf);

    // 4. Launch A: {h = relu(x @ E^T)} || {out = x @ W_L^T + bias}
    //    1024 blocks = 4 blocks/CU = 16 waves/CU.
    k_gemm3<0><<<dim3(B_SZ / 64, 32), 256, 0, stream>>>(
        x2, Ebf, Wbf, biasd, out, x2 + F_IN);

    // 5. Launch B: out += h @ W_R^T   (512 blocks)
    k_gemm3<1><<<dim3(B_SZ / 64, 16), 256, 0, stream>>>(
        x2, Ebf, Wbf, biasd, out, x2 + F_IN);
}

// Round 7
// 55.286 us; speedup vs baseline: 1.2934x; 1.0013x over previous
//
#include <hip/hip_runtime.h>
#include <hip/hip_bf16.h>

#define B_SZ   2048
#define F_IN   1024
#define R_EMB  1024
#define F_OUT  1024
#define F_MID  2048
#define NNZ_E  65536
#define NNZ_W  131072
#define NNZ_B  512

typedef __bf16 bf16x8 __attribute__((ext_vector_type(8)));
typedef float  f32x4  __attribute__((ext_vector_type(4)));

__device__ inline void gload16(const void* g, void* l) {
    __builtin_amdgcn_global_load_lds(
        (const __attribute__((address_space(1))) void*)g,
        (__attribute__((address_space(3))) void*)l, 16, 0, 0);
}

__device__ inline ushort f2bf(float v) {
    __hip_bfloat16 h = __float2bfloat16(v);
    return *reinterpret_cast<ushort*>(&h);
}

__global__ void k_zero4(float4* __restrict__ p, int n) {
    int i = blockIdx.x * blockDim.x + threadIdx.x;
    if (i < n) p[i] = make_float4(0.f, 0.f, 0.f, 0.f);
}

// One launch for all three scatter-adds (blocks partitioned by range).
__global__ void k_scatter_fused(const int* __restrict__ er, const int* __restrict__ ec,
                                const float* __restrict__ ev,
                                const int* __restrict__ wr_, const int* __restrict__ wc_,
                                const float* __restrict__ wv,
                                const int* __restrict__ bi, const float* __restrict__ bv,
                                float* __restrict__ Ef, float* __restrict__ Wf,
                                float* __restrict__ biasd) {
    int b = blockIdx.x, t = threadIdx.x;
    if (b < NNZ_E / 256) {
        int i = b * 256 + t;
        atomicAdd(&Ef[(size_t)er[i] * F_IN + ec[i]], ev[i]);
    } else if (b < NNZ_E / 256 + NNZ_W / 256) {
        int i = (b - NNZ_E / 256) * 256 + t;
        atomicAdd(&Wf[(size_t)wr_[i] * F_MID + wc_[i]], wv[i]);
    } else {
        int i = t;
        atomicAdd(&biasd[bi[i]], bv[i]);
        i += 256;
        atomicAdd(&biasd[bi[i]], bv[i]);
    }
}

// One launch for all three f32->bf16 conversions.
__global__ void k_cvt_fused(const float4* __restrict__ x, ushort* __restrict__ x2,
                            const float4* __restrict__ Ef, ushort* __restrict__ Ebf,
                            const float4* __restrict__ Wf, ushort* __restrict__ Wbf) {
    int b = blockIdx.x, t = threadIdx.x;
    if (b < 2048) {
        int i = b * 256 + t;                 // float4 index into x
        int row = i >> 8, c4 = i & 255;      // 256 float4 per row of 1024
        float4 v = x[i];
        ((ushort4*)x2)[(size_t)row * (F_MID / 4) + c4] =
            make_ushort4(f2bf(v.x), f2bf(v.y), f2bf(v.z), f2bf(v.w));
    } else if (b < 3072) {
        int i = (b - 2048) * 256 + t;
        float4 v = Ef[i];
        ((ushort4*)Ebf)[i] = make_ushort4(f2bf(v.x), f2bf(v.y), f2bf(v.z), f2bf(v.w));
    } else {
        int i = (b - 3072) * 256 + t;
        float4 v = Wf[i];
        ((ushort4*)Wbf)[i] = make_ushort4(f2bf(v.x), f2bf(v.y), f2bf(v.z), f2bf(v.w));
    }
}

// Unified 64x64x64 bf16 MFMA GEMM; 2-buffer COUNTED-vmcnt pipeline (T4):
// per K-tile issue next stage's 4 global_load_lds, s_waitcnt vmcnt(4) (stage t
// done, t+1 still in flight), raw s_barrier, compute, raw s_barrier (no drain).
// Last tile peeled with vmcnt(0).  XOR chunk-swizzle on LDS (pre-swizzled
// global source, linear LDS dest, swizzled ds_read).
//   PHASE 0, by <  16: mode 0  h = relu(x @ E^T)       (bf16 into x2 right half)
//   PHASE 0, by >= 16: mode 1  out = x @ W_L^T + bias  (f32)
//   PHASE 1:           mode 2  out += h @ W_R^T        (f32 RMW)
template <int PHASE>
__global__ __launch_bounds__(256)
void k_gemm3(const ushort* __restrict__ x2,   // [2048][2048] bf16
             const ushort* __restrict__ Ebf,  // [1024][1024] bf16
             const ushort* __restrict__ Wbf,  // [1024][2048] bf16
             const float* __restrict__ biasd, // [1024]
             float* __restrict__ out,         // [2048][1024] f32
             ushort* __restrict__ hOut)       // = x2 + F_IN (disjoint columns)
{
    constexpr int BS = 64, BK = 64, NT = 1024 / BK;
    __shared__ ushort lds[2][2][BS * BK];
    const int tid = threadIdx.x;
    const int w = tid >> 6, l = tid & 63;
    const int wr = w >> 1, wc = w & 1;
    const int la = l & 15;
    const int m0 = blockIdx.x * BS;

    int mode, ldb, n0;
    const ushort* A;
    const ushort* Bm;
    if (PHASE == 0) {
        if (blockIdx.y < 16) {
            mode = 0; A = x2;        Bm = Ebf;        ldb = F_IN;  n0 = blockIdx.y * BS;
        } else {
            mode = 1; A = x2;        Bm = Wbf;        ldb = F_MID; n0 = (blockIdx.y - 16) * BS;
        }
    } else {
        mode = 2;     A = x2 + F_IN; Bm = Wbf + F_IN; ldb = F_MID; n0 = blockIdx.y * BS;
    }

    // Staging: iter i covers 32 rows; lane writing LDS chunk-slot s of row r
    // fetches global chunk s ^ (r&7) (both-sides involution, linear LDS dest).
    const int srow = w * 8 + (l >> 3);
    const int ldst = w * 512 + l * 8;

    f32x4 acc[2][2] = {};

    #define STAGE(buf, k0)                                                        \
        _Pragma("unroll")                                                         \
        for (int i = 0; i < 2; ++i) {                                             \
            int row = i * 32 + srow;                                              \
            int scol = (k0) + ((((l & 7) ^ (row & 7))) << 3);                     \
            gload16(A  + (size_t)(m0 + row) * F_MID + scol,                       \
                    &lds[buf][0][i * 2048 + ldst]);                               \
            gload16(Bm + (size_t)(n0 + row) * ldb + scol,                         \
                    &lds[buf][1][i * 2048 + ldst]);                               \
        }

    auto compute = [&](int cur) {
        const ushort* sA = &lds[cur][0][0];
        const ushort* sB = &lds[cur][1][0];
        #pragma unroll
        for (int ks = 0; ks < 2; ++ks) {
            const int k8 = ks * 4 + (l >> 4);           // 8-elem chunk index
            bf16x8 af[2], bg[2];
            #pragma unroll
            for (int m = 0; m < 2; ++m) {
                int row = wr * 32 + m * 16 + la;
                af[m] = *(const bf16x8*)(sA + row * BK + ((k8 ^ (row & 7)) << 3));
            }
            #pragma unroll
            for (int n = 0; n < 2; ++n) {
                int row = wc * 32 + n * 16 + la;
                bg[n] = *(const bf16x8*)(sB + row * BK + ((k8 ^ (row & 7)) << 3));
            }
            #pragma unroll
            for (int m = 0; m < 2; ++m)
                #pragma unroll
                for (int n = 0; n < 2; ++n)
                    acc[m][n] = __builtin_amdgcn_mfma_f32_16x16x32_bf16(
                        af[m], bg[n], acc[m][n], 0, 0, 0);
        }
    };

    STAGE(0, 0);                                  // stage 0

    // Main loop: tiles 0..NT-2.  Stage t+1 stays in flight across compute(t).
    for (int t = 0; t < NT - 1; ++t) {
        STAGE((t + 1) & 1, (t + 1) * BK);         // stage t+1: 4 loads
        asm volatile("s_waitcnt vmcnt(4)" ::: "memory");   // stage t complete
        __builtin_amdgcn_s_barrier();
        __builtin_amdgcn_sched_barrier(0);
        compute(t & 1);
        __builtin_amdgcn_sched_barrier(0);
        __builtin_amdgcn_s_barrier();             // seal reads before next overwrite
    }
    // Peeled last tile: nothing left to prefetch.
    asm volatile("s_waitcnt vmcnt(0)" ::: "memory");
    __builtin_amdgcn_s_barrier();
    __builtin_amdgcn_sched_barrier(0);
    compute((NT - 1) & 1);
    #undef STAGE

    // C/D layout (verified m89/m91): col = lane&15, row = (lane>>4)*4 + reg.
    const int lr = (l >> 4) * 4;
    #pragma unroll
    for (int m = 0; m < 2; ++m) {
        #pragma unroll
        for (int n = 0; n < 2; ++n) {
            const int col = n0 + wc * 32 + n * 16 + la;
            if (mode == 0) {
                #pragma unroll
                for (int j = 0; j < 4; ++j) {
                    int row = m0 + wr * 32 + m * 16 + lr + j;
                    hOut[(size_t)row * F_MID + col] = f2bf(fmaxf(acc[m][n][j], 0.f));
                }
            } else if (mode == 1) {
                const float bv = biasd[col];
                #pragma unroll
                for (int j = 0; j < 4; ++j) {
                    int row = m0 + wr * 32 + m * 16 + lr + j;
                    out[(size_t)row * F_OUT + col] = acc[m][n][j] + bv;
                }
            } else {
                #pragma unroll
                for (int j = 0; j < 4; ++j) {
                    int row = m0 + wr * 32 + m * 16 + lr + j;
                    out[(size_t)row * F_OUT + col] += acc[m][n][j];
                }
            }
        }
    }
}

extern "C" void kernel_launch(void* const* d_in, const int* in_sizes, int n_in,
                              void* d_out, int out_size, void* d_ws, size_t ws_size,
                              hipStream_t stream) {
    const float* x          = (const float*)d_in[0];
    const int*   embed_rows = (const int*)  d_in[1];
    const int*   embed_cols = (const int*)  d_in[2];
    const float* embed_vals = (const float*)d_in[3];
    const int*   w_rows     = (const int*)  d_in[4];
    const int*   w_cols     = (const int*)  d_in[5];
    const float* w_vals     = (const float*)d_in[6];
    const int*   bias_idx   = (const int*)  d_in[7];
    const float* bias_vals  = (const float*)d_in[8];
    float* out = (float*)d_out;

    // Workspace layout (~26 MB):
    //   [0, 8M)          x2 bf16 [2048][2048]  (left = x, right = relu h)
    //   [8M, 16M)        W_f32 [1024][2048]
    //   [16M, 20M)       E_f32 [1024][1024]
    //   [20M, 20M+4K)    bias f32 [1024]
    //   [20M+4K, 22M+4K) E_bf16 [1024][1024]
    //   [22M+4K, 26M+4K) W_bf16 [1024][2048]
    char* ws = (char*)d_ws;
    ushort* x2    = (ushort*)ws;
    float*  Wf    = (float*)(ws + (8u << 20));
    float*  Ef    = (float*)(ws + (16u << 20));
    float*  biasd = (float*)(ws + (20u << 20));
    ushort* Ebf   = (ushort*)(ws + (20u << 20) + 4096);
    ushort* Wbf   = (ushort*)(ws + (22u << 20) + 4096);

    // 1. zero Wf | Ef | bias (12 MB + 4 KB = 786688 float4).  Own kernel, not
    //    hipMemsetAsync (runtime fill for this size measured ~285 GB/s, round 4).
    k_zero4<<<3073, 256, 0, stream>>>((float4*)(ws + (8u << 20)), 786688);

    // 2. densify all sparse inputs (one launch)
    k_scatter_fused<<<NNZ_E / 256 + NNZ_W / 256 + 1, 256, 0, stream>>>(
        embed_rows, embed_cols, embed_vals,
        w_rows, w_cols, w_vals,
        bias_idx, bias_vals, Ef, Wf, biasd);

    // 3. all f32 -> bf16 conversions (one launch)
    k_cvt_fused<<<5120, 256, 0, stream>>>((const float4*)x, x2,
                                          (const float4*)Ef, Ebf,
                                          (const float4*)Wf, Wbf);

    // 4. Launch A: {h = relu(x @ E^T)} || {out = x @ W_L^T + bias}
    //    1024 blocks = 4 blocks/CU = 16 waves/CU.
    k_gemm3<0><<<dim3(B_SZ / 64, 32), 256, 0, stream>>>(
        x2, Ebf, Wbf, biasd, out, x2 + F_IN);

    // 5. Launch B: out += h @ W_R^T   (512 blocks)
    k_gemm3<1><<<dim3(B_SZ / 64, 16), 256, 0, stream>>>(
        x2, Ebf, Wbf, biasd, out, x2 + F_IN);
}